// Round 1
// baseline (866.046 us; speedup 1.0000x reference)
//
#include <hip/hip_runtime.h>
#include <math.h>

// ConvCapsDAE: fused votes + einsum + transposed-conv scatter.
// votes[b,nkl,c,s,vh] = mu[b,c,s,vh] + sqrt(var[b,c,s,vh]) * noise[b,nkl,c,s,vh]
// out16[u][wh] (per b,nkl,site) = sum_{c,v} Wt[nkl,c,u,v] * votes[c,v,wh]
// recon[b, n, 2i+k, 2j+l, u*4+wh] += out16   (s = j*14+i, nkl = n*9+k*3+l)

#define N_KL 288      // 32 * 3 * 3
#define CW2  6272     // 32 * 14 * 14
#define SPATIAL 196   // 14 * 14

__global__ void sqrt_var_kernel(const float* __restrict__ var,
                                float* __restrict__ sd, int n) {
  int idx = blockIdx.x * blockDim.x + threadIdx.x;
  if (idx < n) sd[idx] = sqrtf(var[idx]);
}

__global__ __launch_bounds__(256) void convcaps_main(
    const float* __restrict__ mu,     // (B, 6272, 16)  == poses flattened
    const float* __restrict__ sd,     // (B, 6272, 16)  sqrt(var) or var
    const float* __restrict__ Wt,     // (288, 32, 16)
    const float* __restrict__ noise,  // (B, 288, 6272, 16)
    float* __restrict__ out,          // (B, 32, 29, 29, 16), pre-zeroed
    int sd_is_var)
{
  const int blk = blockIdx.x;           // b * 288 + nkl
  const int b   = blk / N_KL;
  const int nkl = blk - b * N_KL;
  const int s   = threadIdx.x;          // site = j*14 + i
  if (s >= SPATIAL) return;

  const int j = s / 14;
  const int i = s - j * 14;
  const int n  = nkl / 9;
  const int kl = nkl - n * 9;
  const int k  = kl / 3;
  const int l  = kl - k * 3;

  // Wt address depends only on blockIdx + loop counters -> scalar (SGPR) loads.
  const float* __restrict__ wbase = Wt + (size_t)nkl * 512;
  const float* __restrict__ nb = noise + ((size_t)blk * CW2 + s) * 16;
  const float* __restrict__ mb = mu    + ((size_t)b   * CW2 + s) * 16;
  const float* __restrict__ sb = sd    + ((size_t)b   * CW2 + s) * 16;

  float acc[4][4] = {{0.f,0.f,0.f,0.f},{0.f,0.f,0.f,0.f},
                     {0.f,0.f,0.f,0.f},{0.f,0.f,0.f,0.f}};

  #pragma unroll 2
  for (int c = 0; c < 32; ++c) {
    const float* wc = wbase + c * 16;
    const size_t off = (size_t)c * (SPATIAL * 16);
    #pragma unroll
    for (int v = 0; v < 4; ++v) {
      float4 nz = *(const float4*)(nb + off + v * 4);
      float4 m  = *(const float4*)(mb + off + v * 4);
      float4 sv = *(const float4*)(sb + off + v * 4);
      if (sd_is_var) {  // fallback path only if ws too small
        sv.x = sqrtf(sv.x); sv.y = sqrtf(sv.y);
        sv.z = sqrtf(sv.z); sv.w = sqrtf(sv.w);
      }
      float4 vt;
      vt.x = fmaf(sv.x, nz.x, m.x);
      vt.y = fmaf(sv.y, nz.y, m.y);
      vt.z = fmaf(sv.z, nz.z, m.z);
      vt.w = fmaf(sv.w, nz.w, m.w);
      #pragma unroll
      for (int u = 0; u < 4; ++u) {
        const float wt = wc[u * 4 + v];
        acc[u][0] = fmaf(wt, vt.x, acc[u][0]);
        acc[u][1] = fmaf(wt, vt.y, acc[u][1]);
        acc[u][2] = fmaf(wt, vt.z, acc[u][2]);
        acc[u][3] = fmaf(wt, vt.w, acc[u][3]);
      }
    }
  }

  // scatter: row = 2*i + k, col = 2*j + l; collisions only across blocks
  // with different (k,l) -> atomicAdd (<=4 contributions per element).
  const int r  = 2 * i + k;
  const int cc = 2 * j + l;
  float* ob = out + ((((size_t)b * 32 + n) * 29 + r) * 29 + cc) * 16;
  #pragma unroll
  for (int u = 0; u < 4; ++u) {
    #pragma unroll
    for (int wh = 0; wh < 4; ++wh) {
      atomicAdd(ob + u * 4 + wh, acc[u][wh]);
    }
  }
}

extern "C" void kernel_launch(void* const* d_in, const int* in_sizes, int n_in,
                              void* d_out, int out_size, void* d_ws, size_t ws_size,
                              hipStream_t stream) {
  const float* poses = (const float*)d_in[0];   // (B,32,14,14,16)
  const float* var   = (const float*)d_in[1];   // (B,1,6272,16)
  const float* Wt    = (const float*)d_in[2];   // (32,3,3,32,4,4)
  const float* noise = (const float*)d_in[3];   // (B,288,6272,16)
  float* out = (float*)d_out;

  const int B = in_sizes[0] / (CW2 * 16);       // batch (expect 4)
  const int nvar = in_sizes[1];                 // B * 6272 * 16

  // output is poisoned 0xAA before every timed launch -> zero it.
  hipMemsetAsync(d_out, 0, (size_t)out_size * sizeof(float), stream);

  const float* sdptr;
  int sd_is_var;
  if (ws_size >= (size_t)nvar * sizeof(float)) {
    float* sdv = (float*)d_ws;
    sqrt_var_kernel<<<(nvar + 255) / 256, 256, 0, stream>>>(var, sdv, nvar);
    sdptr = sdv; sd_is_var = 0;
  } else {
    sdptr = var; sd_is_var = 1;
  }

  convcaps_main<<<B * N_KL, 256, 0, stream>>>(poses, sdptr, Wt, noise, out,
                                              sd_is_var);
}

// Round 2
// 627.319 us; speedup vs baseline: 1.3806x; 1.3806x over previous
//
#include <hip/hip_runtime.h>
#include <math.h>

// ConvCapsDAE two-phase:
//  phase1: upd[b,nkl,s,u*4+wh] = sum_{c,v} Wt[nkl,c,u,v] *
//              (mu[b,c,s,v,wh] + sqrt(var[b,c,s,v,wh]) * noise[b,nkl,c,s,v,wh])
//  phase2: out[b,n,r,cc,:] = sum_{k,i:2i+k=r} sum_{l,j:2j+l=cc} upd[b,(n,k,l),(j,i),:]
// No atomics, no memset on the fast path; every output element written once.

#define N_KL 288      // 32 * 3 * 3
#define CW2  6272     // 32 * 14 * 14
#define SPATIAL 196   // 14 * 14

__global__ void sqrt_var_kernel(const float* __restrict__ var,
                                float* __restrict__ sd, int n) {
  int idx = blockIdx.x * blockDim.x + threadIdx.x;
  if (idx < n) sd[idx] = sqrtf(var[idx]);
}

// ---------------- fast path: phase 1 ----------------
// thread = (site, v); 256 threads = 64 sites x 4 v. Lane byte addr = 16*lane
// for noise/mu/sd -> fully coalesced 1KB wave loads.
__global__ __launch_bounds__(256) void convcaps_phase1(
    const float* __restrict__ mu,     // (B, 6272, 16)
    const float* __restrict__ sd,     // (B, 6272, 16)
    const float* __restrict__ Wt,     // (288, 32, 4, 4)
    const float* __restrict__ noise,  // (B, 288, 6272, 16)
    float* __restrict__ upd)          // (B, 288, 196, 16)
{
  __shared__ float wlds[1024];        // 2 nkl x 32c x 4v x 4u (transposed)
  const int tid = threadIdx.x;
  const int BN = N_KL * SPATIAL;      // 56448, divisible by 64 -> b uniform/block

  const long long S0 = (long long)blockIdx.x * 64;
  const int b0   = (int)(S0 / BN);
  const int rem0 = (int)(S0 - (long long)b0 * BN);
  const int nkl0 = rem0 / SPATIAL;
  const int nkl1 = (rem0 + 63) / SPATIAL;   // block spans at most 2 nkl

  // stage Wt[nkl][c][u][v] -> wlds[sel][c][v][u]
  for (int f = tid; f < 1024; f += 256) {
    int sel = f >> 9;
    int rem = f & 511;
    int c = rem >> 4;
    int u = (rem >> 2) & 3;
    int v = rem & 3;
    int nk = sel ? nkl1 : nkl0;
    wlds[sel * 512 + c * 16 + v * 4 + u] = Wt[nk * 512 + rem];
  }
  __syncthreads();

  const int site_local = tid >> 2;
  const int v = tid & 3;
  const int rem = rem0 + site_local;
  const int nkl = rem / SPATIAL;
  const int s = rem - nkl * SPATIAL;
  const int sel = (nkl != nkl0) ? 1 : 0;

  const float* __restrict__ nb =
      noise + ((size_t)(b0 * N_KL + nkl) * CW2 + s) * 16 + v * 4;
  const float* __restrict__ mb = mu + ((size_t)b0 * CW2 + s) * 16 + v * 4;
  const float* __restrict__ sb = sd + ((size_t)b0 * CW2 + s) * 16 + v * 4;
  const float4* __restrict__ wf4 = (const float4*)wlds + sel * 128 + v;

  float4 acc0 = {0.f,0.f,0.f,0.f}, acc1 = {0.f,0.f,0.f,0.f};
  float4 acc2 = {0.f,0.f,0.f,0.f}, acc3 = {0.f,0.f,0.f,0.f};

  #pragma unroll 4
  for (int c = 0; c < 32; ++c) {
    const size_t off = (size_t)c * (SPATIAL * 16);
    float4 nz = *(const float4*)(nb + off);
    float4 m  = *(const float4*)(mb + off);
    float4 sv = *(const float4*)(sb + off);
    float4 w  = wf4[c * 4];
    float4 vt;
    vt.x = fmaf(sv.x, nz.x, m.x);
    vt.y = fmaf(sv.y, nz.y, m.y);
    vt.z = fmaf(sv.z, nz.z, m.z);
    vt.w = fmaf(sv.w, nz.w, m.w);
    acc0.x = fmaf(w.x, vt.x, acc0.x); acc0.y = fmaf(w.x, vt.y, acc0.y);
    acc0.z = fmaf(w.x, vt.z, acc0.z); acc0.w = fmaf(w.x, vt.w, acc0.w);
    acc1.x = fmaf(w.y, vt.x, acc1.x); acc1.y = fmaf(w.y, vt.y, acc1.y);
    acc1.z = fmaf(w.y, vt.z, acc1.z); acc1.w = fmaf(w.y, vt.w, acc1.w);
    acc2.x = fmaf(w.z, vt.x, acc2.x); acc2.y = fmaf(w.z, vt.y, acc2.y);
    acc2.z = fmaf(w.z, vt.z, acc2.z); acc2.w = fmaf(w.z, vt.w, acc2.w);
    acc3.x = fmaf(w.w, vt.x, acc3.x); acc3.y = fmaf(w.w, vt.y, acc3.y);
    acc3.z = fmaf(w.w, vt.z, acc3.z); acc3.w = fmaf(w.w, vt.w, acc3.w);
  }

  // reduce over v across the 4-lane quad (butterfly xor 1, xor 2)
  #define QRED(a) \
    a.x += __shfl_xor(a.x, 1); a.y += __shfl_xor(a.y, 1); \
    a.z += __shfl_xor(a.z, 1); a.w += __shfl_xor(a.w, 1); \
    a.x += __shfl_xor(a.x, 2); a.y += __shfl_xor(a.y, 2); \
    a.z += __shfl_xor(a.z, 2); a.w += __shfl_xor(a.w, 2);
  QRED(acc0) QRED(acc1) QRED(acc2) QRED(acc3)
  #undef QRED

  // lane with v index stores row u = v -> contiguous 1KB wave store
  float4 r01 = (v & 1) ? acc1 : acc0;
  float4 r23 = (v & 1) ? acc3 : acc2;
  float4 myrow = (v & 2) ? r23 : r01;
  *(float4*)(upd + (S0 + site_local) * 16 + v * 4) = myrow;
}

// ---------------- fast path: phase 2 ----------------
// one thread per output float4; gathers <=4 contributing (k,l) sites.
__global__ __launch_bounds__(256) void convcaps_phase2(
    const float* __restrict__ upd, float* __restrict__ out, int total4)
{
  int t = blockIdx.x * 256 + threadIdx.x;
  if (t >= total4) return;
  int q = t & 3;
  int p = t >> 2;
  int cc = p % 29; p /= 29;
  int r  = p % 29; p /= 29;
  int n  = p & 31;
  int b  = p >> 5;

  float4 acc = {0.f, 0.f, 0.f, 0.f};
  #pragma unroll
  for (int k = 0; k < 3; ++k) {
    int ri = r - k;
    if (ri < 0 || (ri & 1)) continue;
    int i = ri >> 1;
    if (i >= 14) continue;
    #pragma unroll
    for (int l = 0; l < 3; ++l) {
      int cj = cc - l;
      if (cj < 0 || (cj & 1)) continue;
      int j = cj >> 1;
      if (j >= 14) continue;
      const float* src = upd +
          (((size_t)b * N_KL + n * 9 + k * 3 + l) * SPATIAL + j * 14 + i) * 16 + q * 4;
      float4 val = *(const float4*)src;
      acc.x += val.x; acc.y += val.y; acc.z += val.z; acc.w += val.w;
    }
  }
  *((float4*)out + t) = acc;
}

// ---------------- fallback (round-1 atomic kernel) ----------------
__global__ __launch_bounds__(256) void convcaps_fallback(
    const float* __restrict__ mu, const float* __restrict__ sd,
    const float* __restrict__ Wt, const float* __restrict__ noise,
    float* __restrict__ out, int sd_is_var)
{
  const int blk = blockIdx.x;
  const int b   = blk / N_KL;
  const int nkl = blk - b * N_KL;
  const int s   = threadIdx.x;
  if (s >= SPATIAL) return;
  const int j = s / 14;
  const int i = s - j * 14;
  const int n  = nkl / 9;
  const int kl = nkl - n * 9;
  const int k  = kl / 3;
  const int l  = kl - k * 3;

  const float* __restrict__ wbase = Wt + (size_t)nkl * 512;
  const float* __restrict__ nb = noise + ((size_t)blk * CW2 + s) * 16;
  const float* __restrict__ mb = mu    + ((size_t)b   * CW2 + s) * 16;
  const float* __restrict__ sb = sd    + ((size_t)b   * CW2 + s) * 16;

  float acc[4][4] = {{0,0,0,0},{0,0,0,0},{0,0,0,0},{0,0,0,0}};
  #pragma unroll 2
  for (int c = 0; c < 32; ++c) {
    const float* wc = wbase + c * 16;
    const size_t off = (size_t)c * (SPATIAL * 16);
    #pragma unroll
    for (int v = 0; v < 4; ++v) {
      float4 nz = *(const float4*)(nb + off + v * 4);
      float4 m  = *(const float4*)(mb + off + v * 4);
      float4 sv = *(const float4*)(sb + off + v * 4);
      if (sd_is_var) {
        sv.x = sqrtf(sv.x); sv.y = sqrtf(sv.y);
        sv.z = sqrtf(sv.z); sv.w = sqrtf(sv.w);
      }
      float4 vt;
      vt.x = fmaf(sv.x, nz.x, m.x);
      vt.y = fmaf(sv.y, nz.y, m.y);
      vt.z = fmaf(sv.z, nz.z, m.z);
      vt.w = fmaf(sv.w, nz.w, m.w);
      #pragma unroll
      for (int u = 0; u < 4; ++u) {
        const float wt = wc[u * 4 + v];
        acc[u][0] = fmaf(wt, vt.x, acc[u][0]);
        acc[u][1] = fmaf(wt, vt.y, acc[u][1]);
        acc[u][2] = fmaf(wt, vt.z, acc[u][2]);
        acc[u][3] = fmaf(wt, vt.w, acc[u][3]);
      }
    }
  }
  const int r  = 2 * i + k;
  const int cc = 2 * j + l;
  float* ob = out + ((((size_t)b * 32 + n) * 29 + r) * 29 + cc) * 16;
  #pragma unroll
  for (int u = 0; u < 4; ++u)
    #pragma unroll
    for (int wh = 0; wh < 4; ++wh)
      atomicAdd(ob + u * 4 + wh, acc[u][wh]);
}

extern "C" void kernel_launch(void* const* d_in, const int* in_sizes, int n_in,
                              void* d_out, int out_size, void* d_ws, size_t ws_size,
                              hipStream_t stream) {
  const float* poses = (const float*)d_in[0];   // (B,32,14,14,16) -> mu (B,6272,16)
  const float* var   = (const float*)d_in[1];   // (B,1,6272,16)
  const float* Wt    = (const float*)d_in[2];   // (288,32,16)
  const float* noise = (const float*)d_in[3];   // (B,288,6272,16)
  float* out = (float*)d_out;

  const int B = in_sizes[0] / (CW2 * 16);
  const int nvar = in_sizes[1];                       // B*6272*16
  const size_t upd_elems = (size_t)B * N_KL * SPATIAL * 16;
  const size_t need = ((size_t)nvar + upd_elems) * sizeof(float);

  if (ws_size >= need) {
    float* sdv  = (float*)d_ws;
    float* updw = sdv + nvar;
    sqrt_var_kernel<<<(nvar + 255) / 256, 256, 0, stream>>>(var, sdv, nvar);
    const int nblk1 = (int)((size_t)B * N_KL * SPATIAL / 64);  // 3528 for B=4
    convcaps_phase1<<<nblk1, 256, 0, stream>>>(poses, sdv, Wt, noise, updw);
    const int total4 = out_size / 4;
    convcaps_phase2<<<(total4 + 255) / 256, 256, 0, stream>>>(updw, out, total4);
  } else {
    hipMemsetAsync(d_out, 0, (size_t)out_size * sizeof(float), stream);
    const float* sdptr;
    int sd_is_var;
    if (ws_size >= (size_t)nvar * sizeof(float)) {
      float* sdv = (float*)d_ws;
      sqrt_var_kernel<<<(nvar + 255) / 256, 256, 0, stream>>>(var, sdv, nvar);
      sdptr = sdv; sd_is_var = 0;
    } else {
      sdptr = var; sd_is_var = 1;
    }
    convcaps_fallback<<<B * N_KL, 256, 0, stream>>>(poses, sdptr, Wt, noise,
                                                    out, sd_is_var);
  }
}

// Round 3
// 622.675 us; speedup vs baseline: 1.3908x; 1.0075x over previous
//
#include <hip/hip_runtime.h>
#include <math.h>

// ConvCapsDAE three-phase:
//  prep : sd = sqrt(var); base[b,nkl,s,u,w] = sum_{c,v} Wt[nkl,c,u,v]*mu[b,c,s,v,w]
//  phase1: upd[b,nkl,s,u,w] = base + sum_{c,v} Wt[nkl,c,u,v]*sd[b,c,s,v,w]*noise[...]
//  phase2: out[b,n,r,cc,:] = sum over contributing (k,l) sites of upd
// No atomics; every output element written exactly once.

#define N_KL 288      // 32 * 3 * 3
#define CW2  6272     // 32 * 14 * 14
#define SPATIAL 196   // 14 * 14

typedef __attribute__((ext_vector_type(4))) float f32x4;

__global__ void sqrt_var_kernel(const float* __restrict__ var,
                                float* __restrict__ sd, int n) {
  int idx = blockIdx.x * blockDim.x + threadIdx.x;
  if (idx < n) sd[idx] = sqrtf(var[idx]);
}

// Shared skeleton: block covers 64 consecutive (nkl,s) sites; thread=(site,v).
// Wt[nkl][c][u][v] staged transposed into LDS as wlds[sel][c][v][u].

// ---------------- base: Sigma Wt*mu (L2-bound, mu reused 288x) ----------------
__global__ __launch_bounds__(256) void convcaps_base(
    const float* __restrict__ mu,     // (B, 6272, 16)
    const float* __restrict__ Wt,     // (288, 512)
    float* __restrict__ base)         // (B, 288, 196, 16)
{
  __shared__ float wlds[1024];
  const int tid = threadIdx.x;
  const int BN = N_KL * SPATIAL;
  const long long S0 = (long long)blockIdx.x * 64;
  const int b0   = (int)(S0 / BN);
  const int rem0 = (int)(S0 - (long long)b0 * BN);
  const int nkl0 = rem0 / SPATIAL;
  const int nkl1 = (rem0 + 63) / SPATIAL;

  for (int f = tid; f < 1024; f += 256) {
    int sel = f >> 9, rem = f & 511;
    int c = rem >> 4, u = (rem >> 2) & 3, v = rem & 3;
    int nk = sel ? nkl1 : nkl0;
    wlds[sel * 512 + c * 16 + v * 4 + u] = Wt[nk * 512 + rem];
  }
  __syncthreads();

  const int site_local = tid >> 2;
  const int v = tid & 3;
  const int rem = rem0 + site_local;
  const int nkl = rem / SPATIAL;
  const int s = rem - nkl * SPATIAL;
  const int sel = (nkl != nkl0) ? 1 : 0;

  const float* __restrict__ mb = mu + ((size_t)b0 * CW2 + s) * 16 + v * 4;
  const f32x4* __restrict__ wf4 = (const f32x4*)wlds + sel * 128 + v;

  f32x4 acc0 = 0.f, acc1 = 0.f, acc2 = 0.f, acc3 = 0.f;
  #pragma unroll 8
  for (int c = 0; c < 32; ++c) {
    const size_t off = (size_t)c * (SPATIAL * 16);
    f32x4 m = *(const f32x4*)(mb + off);
    f32x4 w = wf4[c * 4];
    acc0.x = fmaf(w.x, m.x, acc0.x); acc0.y = fmaf(w.x, m.y, acc0.y);
    acc0.z = fmaf(w.x, m.z, acc0.z); acc0.w = fmaf(w.x, m.w, acc0.w);
    acc1.x = fmaf(w.y, m.x, acc1.x); acc1.y = fmaf(w.y, m.y, acc1.y);
    acc1.z = fmaf(w.y, m.z, acc1.z); acc1.w = fmaf(w.y, m.w, acc1.w);
    acc2.x = fmaf(w.z, m.x, acc2.x); acc2.y = fmaf(w.z, m.y, acc2.y);
    acc2.z = fmaf(w.z, m.z, acc2.z); acc2.w = fmaf(w.z, m.w, acc2.w);
    acc3.x = fmaf(w.w, m.x, acc3.x); acc3.y = fmaf(w.w, m.y, acc3.y);
    acc3.z = fmaf(w.w, m.z, acc3.z); acc3.w = fmaf(w.w, m.w, acc3.w);
  }

  #define QRED(a) \
    a.x += __shfl_xor(a.x, 1); a.y += __shfl_xor(a.y, 1); \
    a.z += __shfl_xor(a.z, 1); a.w += __shfl_xor(a.w, 1); \
    a.x += __shfl_xor(a.x, 2); a.y += __shfl_xor(a.y, 2); \
    a.z += __shfl_xor(a.z, 2); a.w += __shfl_xor(a.w, 2);
  QRED(acc0) QRED(acc1) QRED(acc2) QRED(acc3)

  f32x4 r01 = (v & 1) ? acc1 : acc0;
  f32x4 r23 = (v & 1) ? acc3 : acc2;
  f32x4 my  = (v & 2) ? r23 : r01;
  *(f32x4*)(base + (S0 + site_local) * 16 + v * 4) = my;
}

// ---------------- phase1: base + Sigma Wt*(sd*noise) (HBM-bound) ----------------
__global__ __launch_bounds__(256) void convcaps_phase1(
    const float* __restrict__ sd,     // (B, 6272, 16)
    const float* __restrict__ Wt,     // (288, 512)
    const float* __restrict__ noise,  // (B, 288, 6272, 16)
    const float* __restrict__ base,   // (B, 288, 196, 16)
    float* __restrict__ upd)          // (B, 288, 196, 16)
{
  __shared__ float wlds[1024];
  const int tid = threadIdx.x;
  const int BN = N_KL * SPATIAL;
  const long long S0 = (long long)blockIdx.x * 64;
  const int b0   = (int)(S0 / BN);
  const int rem0 = (int)(S0 - (long long)b0 * BN);
  const int nkl0 = rem0 / SPATIAL;
  const int nkl1 = (rem0 + 63) / SPATIAL;

  for (int f = tid; f < 1024; f += 256) {
    int sel = f >> 9, rem = f & 511;
    int c = rem >> 4, u = (rem >> 2) & 3, v = rem & 3;
    int nk = sel ? nkl1 : nkl0;
    wlds[sel * 512 + c * 16 + v * 4 + u] = Wt[nk * 512 + rem];
  }
  __syncthreads();

  const int site_local = tid >> 2;
  const int v = tid & 3;
  const int rem = rem0 + site_local;
  const int nkl = rem / SPATIAL;
  const int s = rem - nkl * SPATIAL;
  const int sel = (nkl != nkl0) ? 1 : 0;

  const float* __restrict__ nb =
      noise + ((size_t)(b0 * N_KL + nkl) * CW2 + s) * 16 + v * 4;
  const float* __restrict__ sb = sd + ((size_t)b0 * CW2 + s) * 16 + v * 4;
  const f32x4* __restrict__ wf4 = (const f32x4*)wlds + sel * 128 + v;

  f32x4 acc0 = 0.f, acc1 = 0.f, acc2 = 0.f, acc3 = 0.f;
  #pragma unroll 8
  for (int c = 0; c < 32; ++c) {
    const size_t off = (size_t)c * (SPATIAL * 16);
    f32x4 nz = __builtin_nontemporal_load((const f32x4*)(nb + off));
    f32x4 sv = *(const f32x4*)(sb + off);
    f32x4 w  = wf4[c * 4];
    f32x4 vt;
    vt.x = sv.x * nz.x; vt.y = sv.y * nz.y;
    vt.z = sv.z * nz.z; vt.w = sv.w * nz.w;
    acc0.x = fmaf(w.x, vt.x, acc0.x); acc0.y = fmaf(w.x, vt.y, acc0.y);
    acc0.z = fmaf(w.x, vt.z, acc0.z); acc0.w = fmaf(w.x, vt.w, acc0.w);
    acc1.x = fmaf(w.y, vt.x, acc1.x); acc1.y = fmaf(w.y, vt.y, acc1.y);
    acc1.z = fmaf(w.y, vt.z, acc1.z); acc1.w = fmaf(w.y, vt.w, acc1.w);
    acc2.x = fmaf(w.z, vt.x, acc2.x); acc2.y = fmaf(w.z, vt.y, acc2.y);
    acc2.z = fmaf(w.z, vt.z, acc2.z); acc2.w = fmaf(w.z, vt.w, acc2.w);
    acc3.x = fmaf(w.w, vt.x, acc3.x); acc3.y = fmaf(w.w, vt.y, acc3.y);
    acc3.z = fmaf(w.w, vt.z, acc3.z); acc3.w = fmaf(w.w, vt.w, acc3.w);
  }

  QRED(acc0) QRED(acc1) QRED(acc2) QRED(acc3)
  #undef QRED

  f32x4 r01 = (v & 1) ? acc1 : acc0;
  f32x4 r23 = (v & 1) ? acc3 : acc2;
  f32x4 my  = (v & 2) ? r23 : r01;
  const size_t oidx = (S0 + site_local) * 16 + v * 4;
  f32x4 bs = *(const f32x4*)(base + oidx);
  my.x += bs.x; my.y += bs.y; my.z += bs.z; my.w += bs.w;
  *(f32x4*)(upd + oidx) = my;
}

// ---------------- phase2: gather scatter-free ----------------
__global__ __launch_bounds__(256) void convcaps_phase2(
    const float* __restrict__ upd, float* __restrict__ out, int total4)
{
  int t = blockIdx.x * 256 + threadIdx.x;
  if (t >= total4) return;
  int q = t & 3;
  int p = t >> 2;
  int cc = p % 29; p /= 29;
  int r  = p % 29; p /= 29;
  int n  = p & 31;
  int b  = p >> 5;

  f32x4 acc = 0.f;
  #pragma unroll
  for (int k = 0; k < 3; ++k) {
    int ri = r - k;
    if (ri < 0 || (ri & 1)) continue;
    int i = ri >> 1;
    if (i >= 14) continue;
    #pragma unroll
    for (int l = 0; l < 3; ++l) {
      int cj = cc - l;
      if (cj < 0 || (cj & 1)) continue;
      int j = cj >> 1;
      if (j >= 14) continue;
      const float* src = upd +
          (((size_t)b * N_KL + n * 9 + k * 3 + l) * SPATIAL + j * 14 + i) * 16 + q * 4;
      f32x4 val = *(const f32x4*)src;
      acc.x += val.x; acc.y += val.y; acc.z += val.z; acc.w += val.w;
    }
  }
  *((f32x4*)out + t) = acc;
}

// ---------------- fallback (atomic, used only if ws too small) ----------------
__global__ __launch_bounds__(256) void convcaps_fallback(
    const float* __restrict__ mu, const float* __restrict__ sd,
    const float* __restrict__ Wt, const float* __restrict__ noise,
    float* __restrict__ out, int sd_is_var)
{
  const int blk = blockIdx.x;
  const int b   = blk / N_KL;
  const int nkl = blk - b * N_KL;
  const int s   = threadIdx.x;
  if (s >= SPATIAL) return;
  const int j = s / 14;
  const int i = s - j * 14;
  const int n  = nkl / 9;
  const int kl = nkl - n * 9;
  const int k  = kl / 3;
  const int l  = kl - k * 3;

  const float* __restrict__ wbase = Wt + (size_t)nkl * 512;
  const float* __restrict__ nb = noise + ((size_t)blk * CW2 + s) * 16;
  const float* __restrict__ mb = mu    + ((size_t)b   * CW2 + s) * 16;
  const float* __restrict__ sb = sd    + ((size_t)b   * CW2 + s) * 16;

  float acc[4][4] = {{0,0,0,0},{0,0,0,0},{0,0,0,0},{0,0,0,0}};
  #pragma unroll 2
  for (int c = 0; c < 32; ++c) {
    const float* wc = wbase + c * 16;
    const size_t off = (size_t)c * (SPATIAL * 16);
    #pragma unroll
    for (int v = 0; v < 4; ++v) {
      f32x4 nz = *(const f32x4*)(nb + off + v * 4);
      f32x4 m  = *(const f32x4*)(mb + off + v * 4);
      f32x4 sv = *(const f32x4*)(sb + off + v * 4);
      if (sd_is_var) {
        sv.x = sqrtf(sv.x); sv.y = sqrtf(sv.y);
        sv.z = sqrtf(sv.z); sv.w = sqrtf(sv.w);
      }
      f32x4 vt;
      vt.x = fmaf(sv.x, nz.x, m.x);
      vt.y = fmaf(sv.y, nz.y, m.y);
      vt.z = fmaf(sv.z, nz.z, m.z);
      vt.w = fmaf(sv.w, nz.w, m.w);
      #pragma unroll
      for (int u = 0; u < 4; ++u) {
        const float wt = wc[u * 4 + v];
        acc[u][0] = fmaf(wt, vt.x, acc[u][0]);
        acc[u][1] = fmaf(wt, vt.y, acc[u][1]);
        acc[u][2] = fmaf(wt, vt.z, acc[u][2]);
        acc[u][3] = fmaf(wt, vt.w, acc[u][3]);
      }
    }
  }
  const int r  = 2 * i + k;
  const int cc = 2 * j + l;
  float* ob = out + ((((size_t)b * 32 + n) * 29 + r) * 29 + cc) * 16;
  #pragma unroll
  for (int u = 0; u < 4; ++u)
    #pragma unroll
    for (int wh = 0; wh < 4; ++wh)
      atomicAdd(ob + u * 4 + wh, acc[u][wh]);
}

extern "C" void kernel_launch(void* const* d_in, const int* in_sizes, int n_in,
                              void* d_out, int out_size, void* d_ws, size_t ws_size,
                              hipStream_t stream) {
  const float* poses = (const float*)d_in[0];   // (B,32,14,14,16) -> mu (B,6272,16)
  const float* var   = (const float*)d_in[1];   // (B,1,6272,16)
  const float* Wt    = (const float*)d_in[2];   // (288,512)
  const float* noise = (const float*)d_in[3];   // (B,288,6272,16)
  float* out = (float*)d_out;

  const int B = in_sizes[0] / (CW2 * 16);
  const int nvar = in_sizes[1];                       // B*6272*16
  const size_t upd_elems = (size_t)B * N_KL * SPATIAL * 16;
  const size_t need = ((size_t)nvar + 2 * upd_elems) * sizeof(float);

  if (ws_size >= need) {
    float* sdv   = (float*)d_ws;
    float* basew = sdv + nvar;
    float* updw  = basew + upd_elems;
    sqrt_var_kernel<<<(nvar + 255) / 256, 256, 0, stream>>>(var, sdv, nvar);
    const int nblk1 = (int)((size_t)B * N_KL * SPATIAL / 64);  // 3528 for B=4
    convcaps_base<<<nblk1, 256, 0, stream>>>(poses, Wt, basew);
    convcaps_phase1<<<nblk1, 256, 0, stream>>>(sdv, Wt, noise, basew, updw);
    const int total4 = out_size / 4;
    convcaps_phase2<<<(total4 + 255) / 256, 256, 0, stream>>>(updw, out, total4);
  } else {
    hipMemsetAsync(d_out, 0, (size_t)out_size * sizeof(float), stream);
    const float* sdptr;
    int sd_is_var;
    if (ws_size >= (size_t)nvar * sizeof(float)) {
      float* sdv = (float*)d_ws;
      sqrt_var_kernel<<<(nvar + 255) / 256, 256, 0, stream>>>(var, sdv, nvar);
      sdptr = sdv; sd_is_var = 0;
    } else {
      sdptr = var; sd_is_var = 1;
    }
    convcaps_fallback<<<B * N_KL, 256, 0, stream>>>(poses, sdptr, Wt, noise,
                                                    out, sd_is_var);
  }
}